// Round 7
// baseline (2131.916 us; speedup 1.0000x reference)
//
#include <hip/hip_runtime.h>

#define N_ 25000
#define E_ 200000
#define H_ 512
#define OUT_ 250
#define WSZ (H_ * H_)   // 262144 elems per weight matrix

typedef unsigned short u16;
typedef unsigned int u32;
typedef __bf16 bf16x8 __attribute__((ext_vector_type(8)));
typedef float f32x4 __attribute__((ext_vector_type(4)));

__device__ __forceinline__ u16 f2b(float f) {
  union { float f; u32 u; } c; c.f = f;
  u32 r = c.u + 0x7FFFu + ((c.u >> 16) & 1u);
  return (u16)(r >> 16);
}

// ---------------- input conversion: f32 -> bf16 ----------------
__global__ void conv_x(const float* __restrict__ x, u16* __restrict__ xb, int n4) {
  int i = blockIdx.x * 256 + threadIdx.x;
  if (i >= n4) return;
  const float4 v = *(const float4*)(x + (size_t)i * 4);
  ushort4 o;
  o.x = f2b(v.x); o.y = f2b(v.y); o.z = f2b(v.z); o.w = f2b(v.w);
  *(ushort4*)(xb + (size_t)i * 4) = o;
}

// ---------------- weight prep (f32 in, bf16 transposed out) ----------------
__global__ void prep_wt(const float* __restrict__ Wpre, const float* __restrict__ Wpost,
                        const float* __restrict__ Wl, const float* __restrict__ Wr,
                        u16* __restrict__ WT) {
  __shared__ u16 tile[32][33];
  const int id = blockIdx.z;
  const int tx = blockIdx.x, ty = blockIdx.y;
  const int x = threadIdx.x, y = threadIdx.y;
  const float* src = nullptr;
  bool sum3 = false;
  if (id == 0) src = Wpre;
  else if (id == 1) src = Wpost;
  else {
    int li = (id - 2) >> 2, ri = (id - 2) & 3;
    if (ri < 3) src = Wl + (size_t)(li * 3 + ri) * WSZ;
    else { sum3 = true; src = Wr + (size_t)(li * 3) * WSZ; }
  }
#pragma unroll
  for (int i = 0; i < 4; ++i) {
    int row = ty * 32 + y + i * 8;
    int col = tx * 32 + x;
    float f = src[(size_t)row * 512 + col];
    if (sum3) f += src[WSZ + (size_t)row * 512 + col] + src[2 * WSZ + (size_t)row * 512 + col];
    tile[y + i * 8][x] = f2b(f);
  }
  __syncthreads();
#pragma unroll
  for (int i = 0; i < 4; ++i) {
    WT[(size_t)id * WSZ + (tx * 32 + y + i * 8) * 512 + ty * 32 + x] = tile[x][y + i * 8];
  }
}

// W_out [512][250] f32 -> WoutT [256][512] bf16, zero-padded rows 250..255
__global__ void prep_wout(const float* __restrict__ Wout, u16* __restrict__ WoutT) {
  __shared__ u16 tile[32][33];
  const int tx = blockIdx.x, ty = blockIdx.y;
  const int x = threadIdx.x, y = threadIdx.y;
#pragma unroll
  for (int i = 0; i < 4; ++i) {
    int row = ty * 32 + y + i * 8;   // 0..511
    int col = tx * 32 + x;           // 0..255
    tile[y + i * 8][x] = (col < OUT_) ? f2b(Wout[(size_t)row * OUT_ + col]) : (u16)0;
  }
  __syncthreads();
#pragma unroll
  for (int i = 0; i < 4; ++i) {
    WoutT[(tx * 32 + y + i * 8) * 512 + ty * 32 + x] = tile[x][y + i * 8];
  }
}

__global__ void prep_bias(const float* __restrict__ bl, const float* __restrict__ bout,
                          float* __restrict__ blSum, float* __restrict__ bOutF) {
  int t = threadIdx.x;  // block 512
  for (int l = 0; l < 4; ++l)
    blSum[l * 512 + t] = bl[(l * 3 + 0) * 512 + t] + bl[(l * 3 + 1) * 512 + t] +
                         bl[(l * 3 + 2) * 512 + t];
  if (t < 256) bOutF[t] = (t < OUT_) ? bout[t] : 0.0f;
}

// ---------------- CSR build ----------------
__global__ void hist_kernel(const int* __restrict__ edges, int* __restrict__ counts) {
  int idx = blockIdx.x * 256 + threadIdx.x;
  if (idx >= 3 * E_) return;
  int r = idx / E_, e = idx - r * E_;
  int dst = edges[r * 2 * E_ + E_ + e];
  atomicAdd(&counts[r * N_ + dst], 1);
}

// shuffle-based block scan: one block per relation; also emits invdeg
__global__ __launch_bounds__(1024) void scan_kernel(const int* __restrict__ counts,
                                                    int* __restrict__ rowptr,
                                                    int* __restrict__ cursor,
                                                    float* __restrict__ invdeg) {
  const int r = blockIdx.x;
  const int* cnt = counts + r * N_;
  int* rp = rowptr + r * (N_ + 1);
  int* cur = cursor + r * N_;
  __shared__ int wsum[2][16];
  const int tid = threadIdx.x;
  const int wv = tid >> 6, lane = tid & 63;
  int roff = 0;
  int par = 0;
  for (int base = 0; base < N_; base += 1024, par ^= 1) {
    int v = (base + tid < N_) ? cnt[base + tid] : 0;
    int inc = v;
#pragma unroll
    for (int d = 1; d < 64; d <<= 1) {
      int t = __shfl_up(inc, d, 64);
      if (lane >= d) inc += t;
    }
    if (lane == 63) wsum[par][wv] = inc;
    __syncthreads();
    if (tid < 16) {
      int s = wsum[par][tid];
#pragma unroll
      for (int d = 1; d < 16; d <<= 1) {
        int t = __shfl_up(s, d, 64);
        if (tid >= d) s += t;
      }
      wsum[par][tid] = s;
    }
    __syncthreads();
    int woff = (wv == 0) ? 0 : wsum[par][wv - 1];
    int excl = roff + woff + inc - v;
    if (base + tid < N_) {
      rp[base + tid] = excl; cur[base + tid] = excl;
      invdeg[r * N_ + base + tid] = 1.0f / fmaxf((float)v, 1.0f);
    }
    roff += wsum[par][15];
  }
  if (tid == 0) rp[N_] = roff;
}

__global__ void scatter_kernel(const int* __restrict__ edges, int* __restrict__ cursor,
                               int* __restrict__ colidx) {
  int idx = blockIdx.x * 256 + threadIdx.x;
  if (idx >= 3 * E_) return;
  int r = idx / E_, e = idx - r * E_;
  int src = edges[r * 2 * E_ + e];
  int dst = edges[r * 2 * E_ + E_ + e];
  int pos = atomicAdd(&cursor[r * N_ + dst], 1);
  colidx[r * E_ + pos] = src;
}

// ---------------- mean aggregation (feature-chunked, XCD-affine) ----------
__device__ __forceinline__ void acc8(float* acc, uint4 u) {
  union { u32 u; float f; } c;
  c.u = u.x << 16;          acc[0] += c.f;
  c.u = u.x & 0xffff0000u;  acc[1] += c.f;
  c.u = u.y << 16;          acc[2] += c.f;
  c.u = u.y & 0xffff0000u;  acc[3] += c.f;
  c.u = u.z << 16;          acc[4] += c.f;
  c.u = u.z & 0xffff0000u;  acc[5] += c.f;
  c.u = u.w << 16;          acc[6] += c.f;
  c.u = u.w & 0xffff0000u;  acc[7] += c.f;
}

// Feature chunk c pinned to XCD c via blockIdx.x%8 round-robin; per-XCD L2
// holds the whole 3.2MB slice. Wave = 8 nodes x 8 lanes x 16B.
__global__ __launch_bounds__(256) void agg_kernel(const u16* __restrict__ h,
                                                  const int* __restrict__ rowptr,
                                                  const int* __restrict__ colidx,
                                                  const float* __restrict__ invdeg,
                                                  u16* __restrict__ agg) {
  const int chunk = blockIdx.x & 7;          // -> XCD (round-robin heuristic)
  const int nb = blockIdx.x >> 3;
  const int r = blockIdx.y;
  const int wv = threadIdx.x >> 6;
  const int lane = threadIdx.x & 63;
  const int grp = lane >> 3, sub = lane & 7;
  const int node = nb * 32 + wv * 8 + grp;
  if (node >= N_) return;
  const int* rp = rowptr + r * (N_ + 1);
  const int* ci = colidx + r * E_;
  const u16* hb = h + chunk * 64 + sub * 8;  // this lane's 16B within the slice
  const int s = rp[node], e = rp[node + 1];
  float acc[8] = {0.f, 0.f, 0.f, 0.f, 0.f, 0.f, 0.f, 0.f};
  int p = s;
  if (p < e) {
    int src = ci[p];
    uint4 u = *(const uint4*)(hb + (size_t)src * 512);
    for (++p; p < e; ++p) {
      int src2 = ci[p];                       // next gather in flight...
      uint4 u2 = *(const uint4*)(hb + (size_t)src2 * 512);
      acc8(acc, u);                           // ...while unpacking current
      u = u2;
    }
    acc8(acc, u);
  }
  const float sc = invdeg[r * N_ + node];
  uint4 o;
  o.x = (u32)f2b(acc[0] * sc) | ((u32)f2b(acc[1] * sc) << 16);
  o.y = (u32)f2b(acc[2] * sc) | ((u32)f2b(acc[3] * sc) << 16);
  o.z = (u32)f2b(acc[4] * sc) | ((u32)f2b(acc[5] * sc) << 16);
  o.w = (u32)f2b(acc[6] * sc) | ((u32)f2b(acc[7] * sc) << 16);
  *(uint4*)(agg + ((size_t)r * N_ + node) * 512 + chunk * 64 + sub * 8) = o;
}

// ---------------- MFMA GEMM (reg-prefetch pipeline, single 32KB LDS) -------
// C = sum_g A_g[M x 512] @ B_g, B stored transposed [n][k] (bf16).
// K-loop: gload(t+1)->VGPR | compute(t) | barrier | ds_write(t+1) | barrier.
// Loads are thread-private -> barriers need no vmcnt drain; the vmcnt wait is
// a data-dep at ds_write, fully covered by compute(t). This expresses the
// cross-barrier prefetch that global_load_lds structurally cannot.
// LDS: logical 8-elem chunk c of tile row m at slot c^(m&7) (conflict-free).
#define BM 128
#define BN 128
#define BK 64
__global__ __launch_bounds__(256, 3) void gemm_mfma(
    const u16* __restrict__ A0, const u16* __restrict__ A1,
    const u16* __restrict__ A2, const u16* __restrict__ A3,
    const u16* __restrict__ Bt, const float* __restrict__ bias,
    u16* __restrict__ C, float* __restrict__ Cf,
    int M, int G, int ldc, int Nreal, float scale, int leaky) {
  __shared__ __align__(16) u16 As[BM * BK];   // 16 KB
  __shared__ __align__(16) u16 Bs[BN * BK];   // 16 KB
  const int tid = threadIdx.x;
  const int lane = tid & 63;
  const int w = tid >> 6;

  // XCD-aware swizzle of (row-block, col-block)
  const int gx = gridDim.x;
  const int lin = blockIdx.y * gx + blockIdx.x;
  const int gsz = gx * 8;
  const int grp = lin / gsz;
  const int l = lin - grp * gsz;
  const int rem = (int)gridDim.y - grp * 8;
  int by, bx;
  if (rem >= 8) { by = grp * 8 + (l & 7); bx = l >> 3; }
  else          { by = grp * 8 + l % rem; bx = l / rem; }
  const int row0 = by * BM;
  const int col0 = bx * BN;

  // hoisted staging offsets (elements): 4 A-loads + 4 B-loads per thread
  int aOff[4], bOff[4], lOff[4];
#pragma unroll
  for (int i = 0; i < 4; ++i) {
    const int idx = i * 256 + tid;
    const int arow = idx >> 3;
    const int c = (idx & 7) ^ (arow & 7);     // logical chunk for slot idx&7
    int grow = row0 + arow; if (grow >= M) grow = M - 1;
    aOff[i] = grow * 512 + c * 8;
    bOff[i] = (col0 + arow) * 512 + c * 8;
    lOff[i] = idx * 16;                        // LDS byte offset
  }

  // hoisted LDS read offsets
  const int lm = lane & 15;
  const int lk = lane >> 4;                                    // 0..3
  const int x0 = ((lk ^ (lane & 7)) << 3);                     // k0 = 0
  const int x1 = (((4 + lk) ^ (lane & 7)) << 3);               // k0 = 32
  const int wm = (w >> 1) * 64;
  const int wn = (w & 1) * 64;
  int aRow[4], bRow[4];
#pragma unroll
  for (int i = 0; i < 4; ++i) {
    aRow[i] = (wm + i * 16 + lm) * BK;
    bRow[i] = (wn + i * 16 + lm) * BK;
  }

  f32x4 acc[4][4] = {};
  uint4 ra[4], rb[4];

  auto gload = [&](int t) {
    const int g = t >> 3, ki = t & 7;
    const u16* Ag = (g == 0) ? A0 : (g == 1) ? A1 : (g == 2) ? A2 : A3;
    const u16* Ab = Ag + ki * 64;
    const u16* Bb = Bt + ((size_t)g << 18) + ki * 64;
#pragma unroll
    for (int i = 0; i < 4; ++i) {
      ra[i] = *(const uint4*)(Ab + aOff[i]);
      rb[i] = *(const uint4*)(Bb + bOff[i]);
    }
  };
  auto swrite = [&]() {
#pragma unroll
    for (int i = 0; i < 4; ++i) {
      *(uint4*)((char*)As + lOff[i]) = ra[i];
      *(uint4*)((char*)Bs + lOff[i]) = rb[i];
    }
  };
  auto compute = [&]() {
    bf16x8 af[4], bfr[4];
#pragma unroll
    for (int i = 0; i < 4; ++i) {
      af[i]  = *(const bf16x8*)((const char*)As + ((aRow[i] + x0) << 1));
      bfr[i] = *(const bf16x8*)((const char*)Bs + ((bRow[i] + x0) << 1));
    }
#pragma unroll
    for (int i = 0; i < 4; ++i)
#pragma unroll
      for (int j = 0; j < 4; ++j)
        acc[i][j] = __builtin_amdgcn_mfma_f32_16x16x32_bf16(af[i], bfr[j], acc[i][j], 0, 0, 0);
#pragma unroll
    for (int i = 0; i < 4; ++i) {
      af[i]  = *(const bf16x8*)((const char*)As + ((aRow[i] + x1) << 1));
      bfr[i] = *(const bf16x8*)((const char*)Bs + ((bRow[i] + x1) << 1));
    }
#pragma unroll
    for (int i = 0; i < 4; ++i)
#pragma unroll
      for (int j = 0; j < 4; ++j)
        acc[i][j] = __builtin_amdgcn_mfma_f32_16x16x32_bf16(af[i], bfr[j], acc[i][j], 0, 0, 0);
  };

  const int T = G << 3;
  gload(0);
  swrite();
  __syncthreads();
  for (int t = 0; t < T; ++t) {
    if (t + 1 < T) gload(t + 1);   // in flight across compute(t)
    compute();
    __syncthreads();               // all waves done reading LDS(t)
    if (t + 1 < T) {
      swrite();                    // vmcnt data-dep lands here (covered)
      __syncthreads();             // LDS(t+1) visible
    }
  }

  // C/D layout (m89-verified): col = lane&15, row = (lane>>4)*4 + reg
  const int crow_base = row0 + wm + (lk << 2);
  const int ccol_base = col0 + wn + lm;
#pragma unroll
  for (int i = 0; i < 4; ++i) {
#pragma unroll
    for (int j = 0; j < 4; ++j) {
      const int ccol = ccol_base + j * 16;
      const float badd = bias ? bias[ccol] : 0.0f;
#pragma unroll
      for (int rg = 0; rg < 4; ++rg) {
        const int crow = crow_base + i * 16 + rg;
        if (crow < M && ccol < Nreal) {
          float v = (acc[i][j][rg] + badd) * scale;
          if (leaky) v = (v >= 0.0f) ? v : 0.2f * v;
          if (Cf) Cf[(size_t)crow * ldc + ccol] = v;
          else    C[(size_t)crow * ldc + ccol] = f2b(v);
        }
      }
    }
  }
}

// ---------------- launch ----------------
extern "C" void kernel_launch(void* const* d_in, const int* in_sizes, int n_in,
                              void* d_out, int out_size, void* d_ws, size_t ws_size,
                              hipStream_t stream) {
  const float* x     = (const float*)d_in[0];
  const float* Wpre  = (const float*)d_in[1];
  const float* Wpost = (const float*)d_in[2];
  const float* Wl    = (const float*)d_in[3];
  const float* Wr    = (const float*)d_in[4];
  const float* bl    = (const float*)d_in[5];
  const float* Wout  = (const float*)d_in[6];
  const float* bout  = (const float*)d_in[7];
  const int*   edges = (const int*)d_in[8];
  float* out = (float*)d_out;

  char* p = (char*)d_ws;
  auto alloc = [&](size_t b) { void* q = (void*)p; p += (b + 255) & ~(size_t)255; return q; };
  u16*   WT     = (u16*)alloc((size_t)18 * WSZ * 2);
  u16*   WoutT  = (u16*)alloc((size_t)256 * 512 * 2);
  float* blSum  = (float*)alloc(4 * 512 * 4);
  float* bOutF  = (float*)alloc(256 * 4);
  u16*   hA     = (u16*)alloc((size_t)N_ * 512 * 2);
  u16*   hB     = (u16*)alloc((size_t)N_ * 512 * 2);
  u16*   aggb   = (u16*)alloc((size_t)3 * N_ * 512 * 2);
  int*   counts = (int*)alloc(3 * N_ * 4);
  float* invdeg = (float*)alloc(3 * N_ * 4);
  int*   rowptr = (int*)alloc(3 * (N_ + 1) * 4);
  int*   cursor = (int*)alloc(3 * N_ * 4);
  int*   colidx = (int*)alloc((size_t)3 * E_ * 4);
  // xb (bf16 copy of x) aliases aggb: dead before aggb is first written.
  u16*   xb     = aggb;

  hipMemsetAsync(counts, 0, 3 * N_ * 4, stream);
  conv_x<<<(N_ * 512 / 4 + 255) / 256, 256, 0, stream>>>(x, xb, N_ * 512 / 4);
  prep_wt<<<dim3(16, 16, 18), dim3(32, 8), 0, stream>>>(Wpre, Wpost, Wl, Wr, WT);
  prep_wout<<<dim3(8, 16), dim3(32, 8), 0, stream>>>(Wout, WoutT);
  prep_bias<<<1, 512, 0, stream>>>(bl, bout, blSum, bOutF);
  hist_kernel<<<(3 * E_ + 255) / 256, 256, 0, stream>>>(edges, counts);
  scan_kernel<<<3, 1024, 0, stream>>>(counts, rowptr, cursor, invdeg);
  scatter_kernel<<<(3 * E_ + 255) / 256, 256, 0, stream>>>(edges, cursor, colidx);

  const dim3 blk(256);
  const dim3 g512(512 / BN, (N_ + BM - 1) / BM);
  const dim3 gagg(((N_ + 31) / 32) * 8, 3);
  // h = leaky(leaky(x@Wpre)@Wpost)
  gemm_mfma<<<g512, blk, 0, stream>>>(xb, xb, xb, xb, WT, nullptr, hA, nullptr,
                                      N_, 1, 512, 512, 1.0f, 1);
  gemm_mfma<<<g512, blk, 0, stream>>>(hA, hA, hA, hA, WT + WSZ, nullptr, hB, nullptr,
                                      N_, 1, 512, 512, 1.0f, 1);

  u16* hc = hB; u16* hn = hA;
  for (int l = 0; l < 4; ++l) {
    agg_kernel<<<gagg, blk, 0, stream>>>(hc, rowptr, colidx, invdeg, aggb);
    gemm_mfma<<<g512, blk, 0, stream>>>(aggb, aggb + (size_t)N_ * 512, aggb + (size_t)2 * N_ * 512, hc,
                                        WT + (size_t)(2 + 4 * l) * WSZ, blSum + l * 512, hn, nullptr,
                                        N_, 4, 512, 512, 1.0f / 3.0f, 1);
    u16* t = hc; hc = hn; hn = t;
  }
  const dim3 gout(256 / BN, (N_ + BM - 1) / BM);
  gemm_mfma<<<gout, blk, 0, stream>>>(hc, hc, hc, hc, WoutT, bOutF, nullptr, out,
                                      N_, 1, OUT_, OUT_, 1.0f, 0);
}

// Round 8
// 847.754 us; speedup vs baseline: 2.5148x; 2.5148x over previous
//
#include <hip/hip_runtime.h>

#define N_ 25000
#define E_ 200000
#define H_ 512
#define OUT_ 250
#define WSZ (H_ * H_)   // 262144 elems per weight matrix

typedef unsigned short u16;
typedef unsigned int u32;
typedef __bf16 bf16x8 __attribute__((ext_vector_type(8)));
typedef float f32x4 __attribute__((ext_vector_type(4)));

__device__ __forceinline__ u16 f2b(float f) {
  union { float f; u32 u; } c; c.f = f;
  u32 r = c.u + 0x7FFFu + ((c.u >> 16) & 1u);
  return (u16)(r >> 16);
}
// async global->LDS, 16B per lane. LDS dest must be wave-uniform base + lane*16.
__device__ __forceinline__ void async16(const void* g, void* l) {
  __builtin_amdgcn_global_load_lds((__attribute__((address_space(1))) void*)g,
                                   (__attribute__((address_space(3))) void*)l, 16, 0, 0);
}

// ---------------- input conversion: f32 -> bf16 ----------------
__global__ void conv_x(const float* __restrict__ x, u16* __restrict__ xb, int n4) {
  int i = blockIdx.x * 256 + threadIdx.x;
  if (i >= n4) return;
  const float4 v = *(const float4*)(x + (size_t)i * 4);
  ushort4 o;
  o.x = f2b(v.x); o.y = f2b(v.y); o.z = f2b(v.z); o.w = f2b(v.w);
  *(ushort4*)(xb + (size_t)i * 4) = o;
}

// ---------------- weight prep (f32 in, bf16 transposed out) ----------------
__global__ void prep_wt(const float* __restrict__ Wpre, const float* __restrict__ Wpost,
                        const float* __restrict__ Wl, const float* __restrict__ Wr,
                        u16* __restrict__ WT) {
  __shared__ u16 tile[32][33];
  const int id = blockIdx.z;
  const int tx = blockIdx.x, ty = blockIdx.y;
  const int x = threadIdx.x, y = threadIdx.y;
  const float* src = nullptr;
  bool sum3 = false;
  if (id == 0) src = Wpre;
  else if (id == 1) src = Wpost;
  else {
    int li = (id - 2) >> 2, ri = (id - 2) & 3;
    if (ri < 3) src = Wl + (size_t)(li * 3 + ri) * WSZ;
    else { sum3 = true; src = Wr + (size_t)(li * 3) * WSZ; }
  }
#pragma unroll
  for (int i = 0; i < 4; ++i) {
    int row = ty * 32 + y + i * 8;
    int col = tx * 32 + x;
    float f = src[(size_t)row * 512 + col];
    if (sum3) f += src[WSZ + (size_t)row * 512 + col] + src[2 * WSZ + (size_t)row * 512 + col];
    tile[y + i * 8][x] = f2b(f);
  }
  __syncthreads();
#pragma unroll
  for (int i = 0; i < 4; ++i) {
    WT[(size_t)id * WSZ + (tx * 32 + y + i * 8) * 512 + ty * 32 + x] = tile[x][y + i * 8];
  }
}

// W_out [512][250] f32 -> WoutT [256][512] bf16, zero-padded rows 250..255
__global__ void prep_wout(const float* __restrict__ Wout, u16* __restrict__ WoutT) {
  __shared__ u16 tile[32][33];
  const int tx = blockIdx.x, ty = blockIdx.y;
  const int x = threadIdx.x, y = threadIdx.y;
#pragma unroll
  for (int i = 0; i < 4; ++i) {
    int row = ty * 32 + y + i * 8;   // 0..511
    int col = tx * 32 + x;           // 0..255
    tile[y + i * 8][x] = (col < OUT_) ? f2b(Wout[(size_t)row * OUT_ + col]) : (u16)0;
  }
  __syncthreads();
#pragma unroll
  for (int i = 0; i < 4; ++i) {
    WoutT[(tx * 32 + y + i * 8) * 512 + ty * 32 + x] = tile[x][y + i * 8];
  }
}

__global__ void prep_bias(const float* __restrict__ bl, const float* __restrict__ bout,
                          float* __restrict__ blSum, float* __restrict__ bOutF) {
  int t = threadIdx.x;  // block 512
  for (int l = 0; l < 4; ++l)
    blSum[l * 512 + t] = bl[(l * 3 + 0) * 512 + t] + bl[(l * 3 + 1) * 512 + t] +
                         bl[(l * 3 + 2) * 512 + t];
  if (t < 256) bOutF[t] = (t < OUT_) ? bout[t] : 0.0f;
}

// ---------------- CSR build ----------------
__global__ void hist_kernel(const int* __restrict__ edges, int* __restrict__ counts) {
  int idx = blockIdx.x * 256 + threadIdx.x;
  if (idx >= 3 * E_) return;
  int r = idx / E_, e = idx - r * E_;
  int dst = edges[r * 2 * E_ + E_ + e];
  atomicAdd(&counts[r * N_ + dst], 1);
}

// shuffle-based block scan: one block per relation; also emits invdeg
__global__ __launch_bounds__(1024) void scan_kernel(const int* __restrict__ counts,
                                                    int* __restrict__ rowptr,
                                                    int* __restrict__ cursor,
                                                    float* __restrict__ invdeg) {
  const int r = blockIdx.x;
  const int* cnt = counts + r * N_;
  int* rp = rowptr + r * (N_ + 1);
  int* cur = cursor + r * N_;
  __shared__ int wsum[2][16];
  const int tid = threadIdx.x;
  const int wv = tid >> 6, lane = tid & 63;
  int roff = 0;
  int par = 0;
  for (int base = 0; base < N_; base += 1024, par ^= 1) {
    int v = (base + tid < N_) ? cnt[base + tid] : 0;
    int inc = v;
#pragma unroll
    for (int d = 1; d < 64; d <<= 1) {
      int t = __shfl_up(inc, d, 64);
      if (lane >= d) inc += t;
    }
    if (lane == 63) wsum[par][wv] = inc;
    __syncthreads();
    if (tid < 16) {
      int s = wsum[par][tid];
#pragma unroll
      for (int d = 1; d < 16; d <<= 1) {
        int t = __shfl_up(s, d, 64);
        if (tid >= d) s += t;
      }
      wsum[par][tid] = s;
    }
    __syncthreads();
    int woff = (wv == 0) ? 0 : wsum[par][wv - 1];
    int excl = roff + woff + inc - v;
    if (base + tid < N_) {
      rp[base + tid] = excl; cur[base + tid] = excl;
      invdeg[r * N_ + base + tid] = 1.0f / fmaxf((float)v, 1.0f);
    }
    roff += wsum[par][15];
  }
  if (tid == 0) rp[N_] = roff;
}

__global__ void scatter_kernel(const int* __restrict__ edges, int* __restrict__ cursor,
                               int* __restrict__ colidx) {
  int idx = blockIdx.x * 256 + threadIdx.x;
  if (idx >= 3 * E_) return;
  int r = idx / E_, e = idx - r * E_;
  int src = edges[r * 2 * E_ + e];
  int dst = edges[r * 2 * E_ + E_ + e];
  int pos = atomicAdd(&cursor[r * N_ + dst], 1);
  colidx[r * E_ + pos] = src;
}

// ---------------- mean aggregation (feature-chunked, XCD-affine) ----------
__device__ __forceinline__ void acc8(float* acc, uint4 u) {
  union { u32 u; float f; } c;
  c.u = u.x << 16;          acc[0] += c.f;
  c.u = u.x & 0xffff0000u;  acc[1] += c.f;
  c.u = u.y << 16;          acc[2] += c.f;
  c.u = u.y & 0xffff0000u;  acc[3] += c.f;
  c.u = u.z << 16;          acc[4] += c.f;
  c.u = u.z & 0xffff0000u;  acc[5] += c.f;
  c.u = u.w << 16;          acc[6] += c.f;
  c.u = u.w & 0xffff0000u;  acc[7] += c.f;
}

// Feature chunk c pinned to XCD c via blockIdx.x%8 round-robin; per-XCD L2
// holds the whole 3.2MB slice. Wave = 8 nodes x 8 lanes x 16B.
__global__ __launch_bounds__(256) void agg_kernel(const u16* __restrict__ h,
                                                  const int* __restrict__ rowptr,
                                                  const int* __restrict__ colidx,
                                                  const float* __restrict__ invdeg,
                                                  u16* __restrict__ agg) {
  const int chunk = blockIdx.x & 7;          // -> XCD (round-robin heuristic)
  const int nb = blockIdx.x >> 3;
  const int r = blockIdx.y;
  const int wv = threadIdx.x >> 6;
  const int lane = threadIdx.x & 63;
  const int grp = lane >> 3, sub = lane & 7;
  const int node = nb * 32 + wv * 8 + grp;
  if (node >= N_) return;
  const int* rp = rowptr + r * (N_ + 1);
  const int* ci = colidx + r * E_;
  const u16* hb = h + chunk * 64 + sub * 8;  // this lane's 16B within the slice
  const int s = rp[node], e = rp[node + 1];
  float acc[8] = {0.f, 0.f, 0.f, 0.f, 0.f, 0.f, 0.f, 0.f};
  int p = s;
  if (p < e) {
    int src = ci[p];
    uint4 u = *(const uint4*)(hb + (size_t)src * 512);
    for (++p; p < e; ++p) {
      int src2 = ci[p];                       // next gather in flight...
      uint4 u2 = *(const uint4*)(hb + (size_t)src2 * 512);
      acc8(acc, u);                           // ...while unpacking current
      u = u2;
    }
    acc8(acc, u);
  }
  const float sc = invdeg[r * N_ + node];
  uint4 o;
  o.x = (u32)f2b(acc[0] * sc) | ((u32)f2b(acc[1] * sc) << 16);
  o.y = (u32)f2b(acc[2] * sc) | ((u32)f2b(acc[3] * sc) << 16);
  o.z = (u32)f2b(acc[4] * sc) | ((u32)f2b(acc[5] * sc) << 16);
  o.w = (u32)f2b(acc[6] * sc) | ((u32)f2b(acc[7] * sc) << 16);
  *(uint4*)(agg + ((size_t)r * N_ + node) * 512 + chunk * 64 + sub * 8) = o;
}

// ---------------- MFMA GEMM (R5 proven: single-buffer 32KB, swizzled) ------
// C = sum_g A_g[M x 512] @ B_g, B stored transposed [n][k] (bf16).
// LDS: logical 8-elem chunk c of tile row m at slot c^(m&7) (conflict-free).
// Block swizzle: same-row col-blocks land on same XCD (L2 A-reuse).
#define BM 128
#define BN 128
#define BK 64
__global__ __launch_bounds__(256, 4) void gemm_mfma(
    const u16* __restrict__ A0, const u16* __restrict__ A1,
    const u16* __restrict__ A2, const u16* __restrict__ A3,
    const u16* __restrict__ Bt, const float* __restrict__ bias,
    u16* __restrict__ C, float* __restrict__ Cf,
    int M, int G, int ldc, int Nreal, float scale, int leaky) {
  __shared__ __align__(16) u16 As[BM * BK];
  __shared__ __align__(16) u16 Bs[BN * BK];
  const int tid = threadIdx.x;
  const int lane = tid & 63;
  const int w = tid >> 6;

  // XCD-aware swizzle of (row-block, col-block)
  const int gx = gridDim.x;
  const int lin = blockIdx.y * gx + blockIdx.x;
  const int gsz = gx * 8;
  const int grp = lin / gsz;
  const int l = lin - grp * gsz;
  const int rem = (int)gridDim.y - grp * 8;
  int by, bx;
  if (rem >= 8) { by = grp * 8 + (l & 7); bx = l >> 3; }
  else          { by = grp * 8 + l % rem; bx = l / rem; }
  const int row0 = by * BM;
  const int col0 = bx * BN;

  // hoisted staging offsets (elements): 4 A-loads + 4 B-loads per thread
  int aOff[4], bOff[4], lOff[4];
#pragma unroll
  for (int i = 0; i < 4; ++i) {
    const int idx = i * 256 + tid;
    const int arow = idx >> 3;
    const int c = (idx & 7) ^ (arow & 7);     // logical chunk for slot idx&7
    int grow = row0 + arow; if (grow >= M) grow = M - 1;
    aOff[i] = grow * 512 + c * 8;
    bOff[i] = (col0 + arow) * 512 + c * 8;
    lOff[i] = idx * 16;                        // LDS byte offset
  }

  // hoisted LDS read offsets
  const int lm = lane & 15;
  const int lk = lane >> 4;                                    // 0..3
  const int x0 = ((lk ^ (lane & 7)) << 3);                     // k0 = 0
  const int x1 = (((4 + lk) ^ (lane & 7)) << 3);               // k0 = 32
  const int wm = (w >> 1) * 64;
  const int wn = (w & 1) * 64;
  int aRow[4], bRow[4];
#pragma unroll
  for (int i = 0; i < 4; ++i) {
    aRow[i] = (wm + i * 16 + lm) * BK;
    bRow[i] = (wn + i * 16 + lm) * BK;
  }

  f32x4 acc[4][4] = {};

  for (int g = 0; g < G; ++g) {
    const u16* Ag = (g == 0) ? A0 : (g == 1) ? A1 : (g == 2) ? A2 : A3;
    const u16* Bg = Bt + ((size_t)g << 18);
#pragma unroll
    for (int ki = 0; ki < 8; ++ki) {
      const u16* Ab = Ag + ki * 64;   // uniform base advance -> saddr form
      const u16* Bb = Bg + ki * 64;
#pragma unroll
      for (int i = 0; i < 4; ++i) {
        async16(Ab + aOff[i], (char*)As + lOff[i]);
        async16(Bb + bOff[i], (char*)Bs + lOff[i]);
      }
      __syncthreads();
      {
        bf16x8 af[4], bfr[4];
#pragma unroll
        for (int i = 0; i < 4; ++i) {
          af[i]  = *(const bf16x8*)((const char*)As + ((aRow[i] + x0) << 1));
          bfr[i] = *(const bf16x8*)((const char*)Bs + ((bRow[i] + x0) << 1));
        }
#pragma unroll
        for (int i = 0; i < 4; ++i)
#pragma unroll
          for (int j = 0; j < 4; ++j)
            acc[i][j] = __builtin_amdgcn_mfma_f32_16x16x32_bf16(af[i], bfr[j], acc[i][j], 0, 0, 0);
#pragma unroll
        for (int i = 0; i < 4; ++i) {
          af[i]  = *(const bf16x8*)((const char*)As + ((aRow[i] + x1) << 1));
          bfr[i] = *(const bf16x8*)((const char*)Bs + ((bRow[i] + x1) << 1));
        }
#pragma unroll
        for (int i = 0; i < 4; ++i)
#pragma unroll
          for (int j = 0; j < 4; ++j)
            acc[i][j] = __builtin_amdgcn_mfma_f32_16x16x32_bf16(af[i], bfr[j], acc[i][j], 0, 0, 0);
      }
      __syncthreads();
    }
  }

  // C/D layout (m89-verified): col = lane&15, row = (lane>>4)*4 + reg
  const int crow_base = row0 + wm + (lk << 2);
  const int ccol_base = col0 + wn + lm;
#pragma unroll
  for (int i = 0; i < 4; ++i) {
#pragma unroll
    for (int j = 0; j < 4; ++j) {
      const int ccol = ccol_base + j * 16;
      const float badd = bias ? bias[ccol] : 0.0f;
#pragma unroll
      for (int rg = 0; rg < 4; ++rg) {
        const int crow = crow_base + i * 16 + rg;
        if (crow < M && ccol < Nreal) {
          float v = (acc[i][j][rg] + badd) * scale;
          if (leaky) v = (v >= 0.0f) ? v : 0.2f * v;
          if (Cf) Cf[(size_t)crow * ldc + ccol] = v;
          else    C[(size_t)crow * ldc + ccol] = f2b(v);
        }
      }
    }
  }
}

// ---------------- launch ----------------
extern "C" void kernel_launch(void* const* d_in, const int* in_sizes, int n_in,
                              void* d_out, int out_size, void* d_ws, size_t ws_size,
                              hipStream_t stream) {
  const float* x     = (const float*)d_in[0];
  const float* Wpre  = (const float*)d_in[1];
  const float* Wpost = (const float*)d_in[2];
  const float* Wl    = (const float*)d_in[3];
  const float* Wr    = (const float*)d_in[4];
  const float* bl    = (const float*)d_in[5];
  const float* Wout  = (const float*)d_in[6];
  const float* bout  = (const float*)d_in[7];
  const int*   edges = (const int*)d_in[8];
  float* out = (float*)d_out;

  char* p = (char*)d_ws;
  auto alloc = [&](size_t b) { void* q = (void*)p; p += (b + 255) & ~(size_t)255; return q; };
  u16*   WT     = (u16*)alloc((size_t)18 * WSZ * 2);
  u16*   WoutT  = (u16*)alloc((size_t)256 * 512 * 2);
  float* blSum  = (float*)alloc(4 * 512 * 4);
  float* bOutF  = (float*)alloc(256 * 4);
  u16*   hA     = (u16*)alloc((size_t)N_ * 512 * 2);
  u16*   hB     = (u16*)alloc((size_t)N_ * 512 * 2);
  u16*   aggb   = (u16*)alloc((size_t)3 * N_ * 512 * 2);
  int*   counts = (int*)alloc(3 * N_ * 4);
  float* invdeg = (float*)alloc(3 * N_ * 4);
  int*   rowptr = (int*)alloc(3 * (N_ + 1) * 4);
  int*   cursor = (int*)alloc(3 * N_ * 4);
  int*   colidx = (int*)alloc((size_t)3 * E_ * 4);
  // xb (bf16 copy of x) aliases aggb: dead before aggb is first written.
  u16*   xb     = aggb;

  hipMemsetAsync(counts, 0, 3 * N_ * 4, stream);
  conv_x<<<(N_ * 512 / 4 + 255) / 256, 256, 0, stream>>>(x, xb, N_ * 512 / 4);
  prep_wt<<<dim3(16, 16, 18), dim3(32, 8), 0, stream>>>(Wpre, Wpost, Wl, Wr, WT);
  prep_wout<<<dim3(8, 16), dim3(32, 8), 0, stream>>>(Wout, WoutT);
  prep_bias<<<1, 512, 0, stream>>>(bl, bout, blSum, bOutF);
  hist_kernel<<<(3 * E_ + 255) / 256, 256, 0, stream>>>(edges, counts);
  scan_kernel<<<3, 1024, 0, stream>>>(counts, rowptr, cursor, invdeg);
  scatter_kernel<<<(3 * E_ + 255) / 256, 256, 0, stream>>>(edges, cursor, colidx);

  const dim3 blk(256);
  const dim3 g512(512 / BN, (N_ + BM - 1) / BM);
  const dim3 gagg(((N_ + 31) / 32) * 8, 3);
  // h = leaky(leaky(x@Wpre)@Wpost)
  gemm_mfma<<<g512, blk, 0, stream>>>(xb, xb, xb, xb, WT, nullptr, hA, nullptr,
                                      N_, 1, 512, 512, 1.0f, 1);
  gemm_mfma<<<g512, blk, 0, stream>>>(hA, hA, hA, hA, WT + WSZ, nullptr, hB, nullptr,
                                      N_, 1, 512, 512, 1.0f, 1);

  u16* hc = hB; u16* hn = hA;
  for (int l = 0; l < 4; ++l) {
    agg_kernel<<<gagg, blk, 0, stream>>>(hc, rowptr, colidx, invdeg, aggb);
    gemm_mfma<<<g512, blk, 0, stream>>>(aggb, aggb + (size_t)N_ * 512, aggb + (size_t)2 * N_ * 512, hc,
                                        WT + (size_t)(2 + 4 * l) * WSZ, blSum + l * 512, hn, nullptr,
                                        N_, 4, 512, 512, 1.0f / 3.0f, 1);
    u16* t = hc; hc = hn; hn = t;
  }
  const dim3 gout(256 / BN, (N_ + BM - 1) / BM);
  gemm_mfma<<<gout, blk, 0, stream>>>(hc, hc, hc, hc, WoutT, bOutF, nullptr, out,
                                      N_, 1, OUT_, OUT_, 1.0f, 0);
}

// Round 9
// 792.234 us; speedup vs baseline: 2.6910x; 1.0701x over previous
//
#include <hip/hip_runtime.h>

#define N_ 25000
#define E_ 200000
#define H_ 512
#define OUT_ 250
#define WSZ (H_ * H_)   // 262144 elems per weight matrix

typedef unsigned short u16;
typedef unsigned int u32;
typedef __bf16 bf16x8 __attribute__((ext_vector_type(8)));
typedef float f32x4 __attribute__((ext_vector_type(4)));

__device__ __forceinline__ u16 f2b(float f) {
  union { float f; u32 u; } c; c.f = f;
  u32 r = c.u + 0x7FFFu + ((c.u >> 16) & 1u);
  return (u16)(r >> 16);
}
// async global->LDS, 16B per lane. LDS dest must be wave-uniform base + lane*16.
__device__ __forceinline__ void async16(const void* g, void* l) {
  __builtin_amdgcn_global_load_lds((__attribute__((address_space(1))) void*)g,
                                   (__attribute__((address_space(3))) void*)l, 16, 0, 0);
}

// ---------------- fused conv_x + histogram ----------------
__global__ void conv_hist(const float* __restrict__ x, u16* __restrict__ xb,
                          const int* __restrict__ edges, int* __restrict__ counts) {
  const int i = blockIdx.x * 256 + threadIdx.x;
  if (i < 3 * E_) {
    int r = i / E_, e = i - r * E_;
    int dst = edges[r * 2 * E_ + E_ + e];
    atomicAdd(&counts[r * N_ + dst], 1);
  }
  if (i < N_ * 512 / 4) {
    const float4 v = *(const float4*)(x + (size_t)i * 4);
    ushort4 o;
    o.x = f2b(v.x); o.y = f2b(v.y); o.z = f2b(v.z); o.w = f2b(v.w);
    *(ushort4*)(xb + (size_t)i * 4) = o;
  }
}

// ---------------- merged weight/bias prep (f32 in, bf16 transposed out) ----
// id 0..17: WT (id0=W_pre^T, id1=W_post^T, id 2+4l+r (r<3)=Wl[l,r]^T,
//           id 2+4l+3=(sum_r Wr[l,r])^T), [n][k] row-major.
// id 18: WoutT [256][512] (zero-padded rows 250..255). id 19: biases.
__global__ void prep_all(const float* __restrict__ Wpre, const float* __restrict__ Wpost,
                         const float* __restrict__ Wl, const float* __restrict__ Wr,
                         const float* __restrict__ Wout, const float* __restrict__ bl,
                         const float* __restrict__ bout,
                         u16* __restrict__ WT, u16* __restrict__ WoutT,
                         float* __restrict__ blSum, float* __restrict__ bOutF) {
  __shared__ u16 tile[32][33];
  const int id = blockIdx.z;
  const int tx = blockIdx.x, ty = blockIdx.y;
  const int x = threadIdx.x, y = threadIdx.y;
  if (id == 19) {
    if (tx || ty) return;
    const int t = y * 32 + x;
    for (int t0 = t; t0 < 512; t0 += 256) {
      for (int l = 0; l < 4; ++l)
        blSum[l * 512 + t0] = bl[(l * 3 + 0) * 512 + t0] + bl[(l * 3 + 1) * 512 + t0] +
                              bl[(l * 3 + 2) * 512 + t0];
    }
    if (t < 256) bOutF[t] = (t < OUT_) ? bout[t] : 0.0f;
    return;
  }
  if (id == 18) {
    if (tx >= 8) return;
#pragma unroll
    for (int i = 0; i < 4; ++i) {
      int row = ty * 32 + y + i * 8;   // 0..511
      int col = tx * 32 + x;           // 0..255
      tile[y + i * 8][x] = (col < OUT_) ? f2b(Wout[(size_t)row * OUT_ + col]) : (u16)0;
    }
    __syncthreads();
#pragma unroll
    for (int i = 0; i < 4; ++i)
      WoutT[(tx * 32 + y + i * 8) * 512 + ty * 32 + x] = tile[x][y + i * 8];
    return;
  }
  const float* src = nullptr;
  bool sum3 = false;
  if (id == 0) src = Wpre;
  else if (id == 1) src = Wpost;
  else {
    int li = (id - 2) >> 2, ri = (id - 2) & 3;
    if (ri < 3) src = Wl + (size_t)(li * 3 + ri) * WSZ;
    else { sum3 = true; src = Wr + (size_t)(li * 3) * WSZ; }
  }
#pragma unroll
  for (int i = 0; i < 4; ++i) {
    int row = ty * 32 + y + i * 8;
    int col = tx * 32 + x;
    float f = src[(size_t)row * 512 + col];
    if (sum3) f += src[WSZ + (size_t)row * 512 + col] + src[2 * WSZ + (size_t)row * 512 + col];
    tile[y + i * 8][x] = f2b(f);
  }
  __syncthreads();
#pragma unroll
  for (int i = 0; i < 4; ++i)
    WT[(size_t)id * WSZ + (tx * 32 + y + i * 8) * 512 + ty * 32 + x] = tile[x][y + i * 8];
}

// shuffle-based block scan: one block per relation; also emits invdeg
__global__ __launch_bounds__(1024) void scan_kernel(const int* __restrict__ counts,
                                                    int* __restrict__ rowptr,
                                                    int* __restrict__ cursor,
                                                    float* __restrict__ invdeg) {
  const int r = blockIdx.x;
  const int* cnt = counts + r * N_;
  int* rp = rowptr + r * (N_ + 1);
  int* cur = cursor + r * N_;
  __shared__ int wsum[2][16];
  const int tid = threadIdx.x;
  const int wv = tid >> 6, lane = tid & 63;
  int roff = 0;
  int par = 0;
  for (int base = 0; base < N_; base += 1024, par ^= 1) {
    int v = (base + tid < N_) ? cnt[base + tid] : 0;
    int inc = v;
#pragma unroll
    for (int d = 1; d < 64; d <<= 1) {
      int t = __shfl_up(inc, d, 64);
      if (lane >= d) inc += t;
    }
    if (lane == 63) wsum[par][wv] = inc;
    __syncthreads();
    if (tid < 16) {
      int s = wsum[par][tid];
#pragma unroll
      for (int d = 1; d < 16; d <<= 1) {
        int t = __shfl_up(s, d, 64);
        if (tid >= d) s += t;
      }
      wsum[par][tid] = s;
    }
    __syncthreads();
    int woff = (wv == 0) ? 0 : wsum[par][wv - 1];
    int excl = roff + woff + inc - v;
    if (base + tid < N_) {
      rp[base + tid] = excl; cur[base + tid] = excl;
      invdeg[r * N_ + base + tid] = 1.0f / fmaxf((float)v, 1.0f);
    }
    roff += wsum[par][15];
  }
  if (tid == 0) rp[N_] = roff;
}

__global__ void scatter_kernel(const int* __restrict__ edges, int* __restrict__ cursor,
                               int* __restrict__ colidx) {
  int idx = blockIdx.x * 256 + threadIdx.x;
  if (idx >= 3 * E_) return;
  int r = idx / E_, e = idx - r * E_;
  int src = edges[r * 2 * E_ + e];
  int dst = edges[r * 2 * E_ + E_ + e];
  int pos = atomicAdd(&cursor[r * N_ + dst], 1);
  colidx[r * E_ + pos] = src;
}

// ---------------- mean aggregation (feature-chunked, XCD-affine) ----------
__device__ __forceinline__ void acc8(float* acc, uint4 u) {
  union { u32 u; float f; } c;
  c.u = u.x << 16;          acc[0] += c.f;
  c.u = u.x & 0xffff0000u;  acc[1] += c.f;
  c.u = u.y << 16;          acc[2] += c.f;
  c.u = u.y & 0xffff0000u;  acc[3] += c.f;
  c.u = u.z << 16;          acc[4] += c.f;
  c.u = u.z & 0xffff0000u;  acc[5] += c.f;
  c.u = u.w << 16;          acc[6] += c.f;
  c.u = u.w & 0xffff0000u;  acc[7] += c.f;
}

// Feature chunk c pinned to XCD c via blockIdx.x%8 round-robin; per-XCD L2
// holds the whole 3.2MB slice. Wave = 8 nodes x 8 lanes x 16B.
// 4-deep gather pipeline (deg~8 -> 2 batches).
__global__ __launch_bounds__(256) void agg_kernel(const u16* __restrict__ h,
                                                  const int* __restrict__ rowptr,
                                                  const int* __restrict__ colidx,
                                                  const float* __restrict__ invdeg,
                                                  u16* __restrict__ agg) {
  const int chunk = blockIdx.x & 7;          // -> XCD (round-robin heuristic)
  const int nb = blockIdx.x >> 3;
  const int r = blockIdx.y;
  const int wv = threadIdx.x >> 6;
  const int lane = threadIdx.x & 63;
  const int grp = lane >> 3, sub = lane & 7;
  const int node = nb * 32 + wv * 8 + grp;
  if (node >= N_) return;
  const int* rp = rowptr + r * (N_ + 1);
  const int* ci = colidx + r * E_;
  const u16* hb = h + chunk * 64 + sub * 8;  // this lane's 16B within the slice
  const int s = rp[node], e = rp[node + 1];
  float acc[8] = {0.f, 0.f, 0.f, 0.f, 0.f, 0.f, 0.f, 0.f};
  int p = s;
  for (; p + 4 <= e; p += 4) {
    int s0 = ci[p], s1 = ci[p + 1], s2 = ci[p + 2], s3 = ci[p + 3];
    uint4 u0 = *(const uint4*)(hb + (size_t)s0 * 512);
    uint4 u1 = *(const uint4*)(hb + (size_t)s1 * 512);
    uint4 u2 = *(const uint4*)(hb + (size_t)s2 * 512);
    uint4 u3 = *(const uint4*)(hb + (size_t)s3 * 512);
    acc8(acc, u0); acc8(acc, u1); acc8(acc, u2); acc8(acc, u3);
  }
  for (; p < e; ++p) acc8(acc, *(const uint4*)(hb + (size_t)ci[p] * 512));
  const float sc = invdeg[r * N_ + node];
  uint4 o;
  o.x = (u32)f2b(acc[0] * sc) | ((u32)f2b(acc[1] * sc) << 16);
  o.y = (u32)f2b(acc[2] * sc) | ((u32)f2b(acc[3] * sc) << 16);
  o.z = (u32)f2b(acc[4] * sc) | ((u32)f2b(acc[5] * sc) << 16);
  o.w = (u32)f2b(acc[6] * sc) | ((u32)f2b(acc[7] * sc) << 16);
  *(uint4*)(agg + ((size_t)r * N_ + node) * 512 + chunk * 64 + sub * 8) = o;
}

// ---------------- MFMA GEMM (R5 K-loop + LDS-coalesced bf16 epilogue) ------
// C = sum_g A_g[M x 512] @ B_g, B stored transposed [n][k] (bf16).
// LDS: logical 8-elem chunk c of tile row m at slot c^(m&7) (conflict-free).
// Block swizzle: same-row col-blocks land on same XCD (L2 A-reuse).
// bf16 epilogue: acc -> LDS (stride 136 u16: 16B-aligned rows, spread banks)
// -> coalesced dwordx4 stores (fixes 2-B scattered stores, WRITE inflation).
#define BM 128
#define BN 128
#define BK 64
#define CSTRIDE 136
__global__ __launch_bounds__(256, 4) void gemm_mfma(
    const u16* __restrict__ A0, const u16* __restrict__ A1,
    const u16* __restrict__ A2, const u16* __restrict__ A3,
    const u16* __restrict__ Bt, const float* __restrict__ bias,
    u16* __restrict__ C, float* __restrict__ Cf,
    int M, int G, int ldc, int Nreal, float scale, int leaky) {
  __shared__ __align__(16) u16 shmem[BM * CSTRIDE];  // 34 KB; As/Bs carved below
  u16* As = shmem;                    // BM*BK = 8192 u16
  u16* Bs = shmem + BM * BK;          // BN*BK = 8192 u16
  const int tid = threadIdx.x;
  const int lane = tid & 63;
  const int w = tid >> 6;

  // XCD-aware swizzle of (row-block, col-block)
  const int gx = gridDim.x;
  const int lin = blockIdx.y * gx + blockIdx.x;
  const int gsz = gx * 8;
  const int grp = lin / gsz;
  const int l = lin - grp * gsz;
  const int rem = (int)gridDim.y - grp * 8;
  int by, bx;
  if (rem >= 8) { by = grp * 8 + (l & 7); bx = l >> 3; }
  else          { by = grp * 8 + l % rem; bx = l / rem; }
  const int row0 = by * BM;
  const int col0 = bx * BN;

  // hoisted staging offsets (elements): 4 A-loads + 4 B-loads per thread
  int aOff[4], bOff[4], lOff[4];
#pragma unroll
  for (int i = 0; i < 4; ++i) {
    const int idx = i * 256 + tid;
    const int arow = idx >> 3;
    const int c = (idx & 7) ^ (arow & 7);     // logical chunk for slot idx&7
    int grow = row0 + arow; if (grow >= M) grow = M - 1;
    aOff[i] = grow * 512 + c * 8;
    bOff[i] = (col0 + arow) * 512 + c * 8;
    lOff[i] = idx * 16;                        // LDS byte offset
  }

  // hoisted LDS read offsets
  const int lm = lane & 15;
  const int lk = lane >> 4;                                    // 0..3
  const int x0 = ((lk ^ (lane & 7)) << 3);                     // k0 = 0
  const int x1 = (((4 + lk) ^ (lane & 7)) << 3);               // k0 = 32
  const int wm = (w >> 1) * 64;
  const int wn = (w & 1) * 64;
  int aRow[4], bRow[4];
#pragma unroll
  for (int i = 0; i < 4; ++i) {
    aRow[i] = (wm + i * 16 + lm) * BK;
    bRow[i] = (wn + i * 16 + lm) * BK;
  }

  f32x4 acc[4][4] = {};

  for (int g = 0; g < G; ++g) {
    const u16* Ag = (g == 0) ? A0 : (g == 1) ? A1 : (g == 2) ? A2 : A3;
    const u16* Bg = Bt + ((size_t)g << 18);
#pragma unroll
    for (int ki = 0; ki < 8; ++ki) {
      const u16* Ab = Ag + ki * 64;   // uniform base advance -> saddr form
      const u16* Bb = Bg + ki * 64;
#pragma unroll
      for (int i = 0; i < 4; ++i) {
        async16(Ab + aOff[i], (char*)As + lOff[i]);
        async16(Bb + bOff[i], (char*)Bs + lOff[i]);
      }
      __syncthreads();
      {
        bf16x8 af[4], bfr[4];
#pragma unroll
        for (int i = 0; i < 4; ++i) {
          af[i]  = *(const bf16x8*)((const char*)As + ((aRow[i] + x0) << 1));
          bfr[i] = *(const bf16x8*)((const char*)Bs + ((bRow[i] + x0) << 1));
        }
#pragma unroll
        for (int i = 0; i < 4; ++i)
#pragma unroll
          for (int j = 0; j < 4; ++j)
            acc[i][j] = __builtin_amdgcn_mfma_f32_16x16x32_bf16(af[i], bfr[j], acc[i][j], 0, 0, 0);
#pragma unroll
        for (int i = 0; i < 4; ++i) {
          af[i]  = *(const bf16x8*)((const char*)As + ((aRow[i] + x1) << 1));
          bfr[i] = *(const bf16x8*)((const char*)Bs + ((bRow[i] + x1) << 1));
        }
#pragma unroll
        for (int i = 0; i < 4; ++i)
#pragma unroll
          for (int j = 0; j < 4; ++j)
            acc[i][j] = __builtin_amdgcn_mfma_f32_16x16x32_bf16(af[i], bfr[j], acc[i][j], 0, 0, 0);
      }
      __syncthreads();
    }
  }

  // C/D layout (m89-verified): col = lane&15, row = (lane>>4)*4 + reg
  if (Cf) {  // fp32 scalar path (out-GEMM; masked, small)
    const int crow_base = row0 + wm + (lk << 2);
    const int ccol_base = col0 + wn + lm;
#pragma unroll
    for (int i = 0; i < 4; ++i) {
#pragma unroll
      for (int j = 0; j < 4; ++j) {
        const int ccol = ccol_base + j * 16;
        const float badd = bias ? bias[ccol] : 0.0f;
#pragma unroll
        for (int rg = 0; rg < 4; ++rg) {
          const int crow = crow_base + i * 16 + rg;
          if (crow < M && ccol < Nreal) {
            float v = (acc[i][j][rg] + badd) * scale;
            if (leaky) v = (v >= 0.0f) ? v : 0.2f * v;
            Cf[(size_t)crow * ldc + ccol] = v;
          }
        }
      }
    }
    return;
  }
  // bf16 path: transpose through LDS, store coalesced (Nreal==ldc==512 here)
  {
    const int lrow_base = wm + (lk << 2);
    const int lcol_base = wn + lm;
#pragma unroll
    for (int i = 0; i < 4; ++i) {
#pragma unroll
      for (int j = 0; j < 4; ++j) {
        const int lcol = lcol_base + j * 16;
        const float badd = bias ? bias[col0 + lcol] : 0.0f;
#pragma unroll
        for (int rg = 0; rg < 4; ++rg) {
          const int lrow = lrow_base + i * 16 + rg;
          float v = (acc[i][j][rg] + badd) * scale;
          if (leaky) v = (v >= 0.0f) ? v : 0.2f * v;
          shmem[lrow * CSTRIDE + lcol] = f2b(v);
        }
      }
    }
    __syncthreads();
    const int rr = tid >> 4;           // 0..15
    const int c8 = (tid & 15) * 8;     // col chunk (8 u16 = 16 B)
#pragma unroll
    for (int pass = 0; pass < 8; ++pass) {
      const int r = pass * 16 + rr;    // 0..127
      const int crow = row0 + r;
      if (crow < M) {
        uint4 v = *(const uint4*)&shmem[r * CSTRIDE + c8];
        *(uint4*)(C + (size_t)crow * ldc + col0 + c8) = v;
      }
    }
  }
}

// ---------------- launch ----------------
extern "C" void kernel_launch(void* const* d_in, const int* in_sizes, int n_in,
                              void* d_out, int out_size, void* d_ws, size_t ws_size,
                              hipStream_t stream) {
  const float* x     = (const float*)d_in[0];
  const float* Wpre  = (const float*)d_in[1];
  const float* Wpost = (const float*)d_in[2];
  const float* Wl    = (const float*)d_in[3];
  const float* Wr    = (const float*)d_in[4];
  const float* bl    = (const float*)d_in[5];
  const float* Wout  = (const float*)d_in[6];
  const float* bout  = (const float*)d_in[7];
  const int*   edges = (const int*)d_in[8];
  float* out = (float*)d_out;

  char* p = (char*)d_ws;
  auto alloc = [&](size_t b) { void* q = (void*)p; p += (b + 255) & ~(size_t)255; return q; };
  u16*   WT     = (u16*)alloc((size_t)18 * WSZ * 2);
  u16*   WoutT  = (u16*)alloc((size_t)256 * 512 * 2);
  float* blSum  = (float*)alloc(4 * 512 * 4);
  float* bOutF  = (float*)alloc(256 * 4);
  u16*   hA     = (u16*)alloc((size_t)N_ * 512 * 2);
  u16*   hB     = (u16*)alloc((size_t)N_ * 512 * 2);
  u16*   aggb   = (u16*)alloc((size_t)3 * N_ * 512 * 2);
  int*   counts = (int*)alloc(3 * N_ * 4);
  float* invdeg = (float*)alloc(3 * N_ * 4);
  int*   rowptr = (int*)alloc(3 * (N_ + 1) * 4);
  int*   cursor = (int*)alloc(3 * N_ * 4);
  int*   colidx = (int*)alloc((size_t)3 * E_ * 4);
  // xb (bf16 copy of x) aliases aggb: dead before aggb is first written.
  u16*   xb     = aggb;

  hipMemsetAsync(counts, 0, 3 * N_ * 4, stream);
  conv_hist<<<(N_ * 512 / 4 + 255) / 256, 256, 0, stream>>>(x, xb, edges, counts);
  prep_all<<<dim3(16, 16, 20), dim3(32, 8), 0, stream>>>(Wpre, Wpost, Wl, Wr, Wout, bl, bout,
                                                          WT, WoutT, blSum, bOutF);
  scan_kernel<<<3, 1024, 0, stream>>>(counts, rowptr, cursor, invdeg);
  scatter_kernel<<<(3 * E_ + 255) / 256, 256, 0, stream>>>(edges, cursor, colidx);

  const dim3 blk(256);
  const dim3 g512(512 / BN, (N_ + BM - 1) / BM);
  const dim3 gagg(((N_ + 31) / 32) * 8, 3);
  // h = leaky(leaky(x@Wpre)@Wpost)
  gemm_mfma<<<g512, blk, 0, stream>>>(xb, xb, xb, xb, WT, nullptr, hA, nullptr,
                                      N_, 1, 512, 512, 1.0f, 1);
  gemm_mfma<<<g512, blk, 0, stream>>>(hA, hA, hA, hA, WT + WSZ, nullptr, hB, nullptr,
                                      N_, 1, 512, 512, 1.0f, 1);

  u16* hc = hB; u16* hn = hA;
  for (int l = 0; l < 4; ++l) {
    agg_kernel<<<gagg, blk, 0, stream>>>(hc, rowptr, colidx, invdeg, aggb);
    gemm_mfma<<<g512, blk, 0, stream>>>(aggb, aggb + (size_t)N_ * 512, aggb + (size_t)2 * N_ * 512, hc,
                                        WT + (size_t)(2 + 4 * l) * WSZ, blSum + l * 512, hn, nullptr,
                                        N_, 4, 512, 512, 1.0f / 3.0f, 1);
    u16* t = hc; hc = hn; hn = t;
  }
  const dim3 gout(256 / BN, (N_ + BM - 1) / BM);
  gemm_mfma<<<gout, blk, 0, stream>>>(hc, hc, hc, hc, WoutT, bOutF, nullptr, out,
                                      N_, 1, OUT_, OUT_, 1.0f, 0);
}